// Round 8
// baseline (129.380 us; speedup 1.0000x reference)
//
#include <hip/hip_runtime.h>
#include <math.h>

static constexpr int kN = 8192;
static constexpr int kC = 128;
static constexpr int kB = 16;
static constexpr float kScale = 0.5f / 1048576.0f; // 1/(C*N) * 0.5 (Y-build fold)
static constexpr double kTwoPi = 6.28318530717958647692;

#define C8  0.70710678118654752f
#define CP8 0.92387953251128676f
#define SP8 0.38268343236508977f

typedef float v2f __attribute__((ext_vector_type(2)));

__device__ __forceinline__ v2f mk2(float x, float y){ v2f r; r.x=x; r.y=y; return r; }
__device__ __forceinline__ v2f imul(v2f a){ return mk2(-a.y, a.x); }   // +i*a
__device__ __forceinline__ v2f mimul(v2f a){ return mk2(a.y, -a.x); }  // -i*a
__device__ __forceinline__ v2f cconj(v2f a){ return mk2(a.x, -a.y); }
__device__ __forceinline__ v2f cmul(v2f a, v2f b){
    return mk2(a.x*b.x - a.y*b.y, a.x*b.y + a.y*b.x);
}

// swizzle: phys = n ^ ((n>>4)&15). Verified conflict-floor for all three
// stage patterns (stride-256, mixed, stride-16 contiguous) at b64 width.
__device__ __forceinline__ int swz(int n){ return n ^ ((n>>4)&15); }

// e^{+2pi i m/4096}, m in [0,2048)
__device__ __forceinline__ v2f W2048(const v2f* T, int m){
    v2f tt = T[m & 1023];
    return (m & 1024) ? imul(tt) : tt;
}

// slot s = 4j+m holds A[4m+j]; A[k] lives at reg REV(k)
#define REV(k) ((((k)&3)<<2)|((k)>>2))

template<int SGN>
__device__ __forceinline__ void dft4(v2f&a, v2f&b, v2f&c, v2f&d){
    v2f t0=a+c, t1=a-c, t2=b+d, t3=b-d;
    v2f j3 = (SGN>0) ? imul(t3) : mimul(t3);
    a = t0+t2; b = t1+j3; c = t0-t2; d = t1-j3;
}

// 16-pt DFT, A_k = sum_j in[j] e^{SGN*2pi i jk/16}; in natural, out via REV.
template<int SGN>
__device__ __forceinline__ void dft16(v2f* v){
    dft4<SGN>(v[0], v[4], v[8],  v[12]);
    dft4<SGN>(v[1], v[5], v[9],  v[13]);
    dft4<SGN>(v[2], v[6], v[10], v[14]);
    dft4<SGN>(v[3], v[7], v[11], v[15]);
    const float sg = (SGN>0)? 1.f : -1.f;
    const v2f W1 = mk2(CP8,  sg*SP8);   // W16^1
    const v2f W2 = mk2(C8,   sg*C8);    // W16^2
    const v2f W3 = mk2(SP8,  sg*CP8);   // W16^3
    const v2f W6 = mk2(-C8,  sg*C8);    // W16^6
    const v2f W9 = mk2(-CP8, -sg*SP8);  // W16^9
    v[5]  = cmul(v[5],  W1);
    v[9]  = cmul(v[9],  W2);
    v[13] = cmul(v[13], W3);
    v[6]  = cmul(v[6],  W2);
    v[10] = (SGN>0)? imul(v[10]) : mimul(v[10]);   // W16^4
    v[14] = cmul(v[14], W6);
    v[7]  = cmul(v[7],  W3);
    v[11] = cmul(v[11], W6);
    v[15] = cmul(v[15], W9);
    dft4<SGN>(v[0],  v[1],  v[2],  v[3]);
    dft4<SGN>(v[4],  v[5],  v[6],  v[7]);
    dft4<SGN>(v[8],  v[9],  v[10], v[11]);
    dft4<SGN>(v[12], v[13], v[14], v[15]);
}

// DIF stage twiddle: A[m] (at reg REV(m)) *= w^m, m=1..15
__device__ __forceinline__ void twid_dif(v2f* v, v2f w1){
    v2f w2=cmul(w1,w1), w3=cmul(w2,w1), w4=cmul(w2,w2);
    v2f w5=cmul(w2,w3), w6=cmul(w3,w3), w7=cmul(w3,w4), w8=cmul(w4,w4);
    v2f w9=cmul(w4,w5), w10=cmul(w5,w5), w11=cmul(w5,w6), w12=cmul(w6,w6);
    v2f w13=cmul(w6,w7), w14=cmul(w7,w7), w15=cmul(w7,w8);
    v[4] =cmul(v[4], w1);  v[8] =cmul(v[8], w2);  v[12]=cmul(v[12],w3);
    v[1] =cmul(v[1], w4);  v[5] =cmul(v[5], w5);  v[9] =cmul(v[9], w6);
    v[13]=cmul(v[13],w7);  v[2] =cmul(v[2], w8);  v[6] =cmul(v[6], w9);
    v[10]=cmul(v[10],w10); v[14]=cmul(v[14],w11); v[3] =cmul(v[3], w12);
    v[7] =cmul(v[7], w13); v[11]=cmul(v[11],w14); v[15]=cmul(v[15],w15);
}

// DIT stage twiddle (before dft): v[j] *= w^j, natural index
__device__ __forceinline__ void twid_dit(v2f* v, v2f w1){
    v2f w2=cmul(w1,w1), w3=cmul(w2,w1), w4=cmul(w2,w2);
    v2f w5=cmul(w2,w3), w6=cmul(w3,w3), w7=cmul(w3,w4), w8=cmul(w4,w4);
    v2f w9=cmul(w4,w5), w10=cmul(w5,w5), w11=cmul(w5,w6), w12=cmul(w6,w6);
    v2f w13=cmul(w6,w7), w14=cmul(w7,w7), w15=cmul(w7,w8);
    v[1] =cmul(v[1], w1);  v[2] =cmul(v[2], w2);  v[3] =cmul(v[3], w3);
    v[4] =cmul(v[4], w4);  v[5] =cmul(v[5], w5);  v[6] =cmul(v[6], w6);
    v[7] =cmul(v[7], w7);  v[8] =cmul(v[8], w8);  v[9] =cmul(v[9], w9);
    v[10]=cmul(v[10],w10); v[11]=cmul(v[11],w11); v[12]=cmul(v[12],w12);
    v[13]=cmul(v[13],w13); v[14]=cmul(v[14],w14); v[15]=cmul(v[15],w15);
}

// tanh-form GELU on both components
__device__ __forceinline__ v2f gelu2(v2f v){
    v2f z = v * (0.7978845608028654f + 0.0356774081363001f * v * v);
    float e0 = __builtin_amdgcn_exp2f(-2.8853900817779268f * z.x);
    float e1 = __builtin_amdgcn_exp2f(-2.8853900817779268f * z.y);
    return mk2(v.x / (1.0f + e0), v.y / (1.0f + e1));
}

// Kernel 1: one row per 256-thread WG, radix-16^3, 16 elems/thread.
// Hermitian-pack -> 4096-pt inverse FFT (DIF stages A,B,C) -> instnorm+GELU
// in regs -> forward FFT (DIT C',B',A') -> write Z' (natural order) to global.
// LDS = 32KiB buf + 8KiB T = 40960B -> 4 WG/CU.
__global__ __launch_bounds__(256, 4) void k1_row(
    const float* __restrict__ xr, const float* __restrict__ xi,
    const float* __restrict__ gamma, const float* __restrict__ beta,
    float* __restrict__ outR, float* __restrict__ outI)
{
    __shared__ v2f buf[4096];  // 32 KiB, swizzled
    __shared__ v2f T[1024];    // 8 KiB: e^{+2pi i m/4096}

    const int p   = threadIdx.x;        // 0..255
    const int row = blockIdx.x;
    const int ch  = row & (kC-1);

    for (int i = p; i < 1024; i += 256) {
        float s, c;
        sincosf((float)(kTwoPi/4096.0 * (double)i), &s, &c);
        T[i] = mk2(c, s);
    }
    __syncthreads();                                  // (1) T ready

    const v2f E = mk2(0.9999997058628822f, 7.669903187427045e-4f); // e^{+i pi/4096}
    const int i0 = ((p>>4)<<8) + (p&15);              // stage-B group base
    const v2f wB = T[(p&15)<<4];                      // W256^{p&15}

    v2f v[16];

    const float* rR = xr + (size_t)row * kN;
    const float* rI = xi + (size_t)row * kN;

    // ---- pre-combine (0.5 dropped; instnorm absorbs) + DIF stage A (h=256) ----
    #pragma unroll
    for (int j = 0; j < 16; ++j) {
        int k   = p + (j<<8);
        int km  = (kN - k) & (kN-1);
        int km2 = 4096 - k;
        v2f w = W2048(T, k>>1);
        if (p & 1) w = cmul(w, E);
        v2f Hk  = mk2(rR[k]+rR[km],       rI[k]-rI[km]);
        v2f Hk2 = mk2(rR[k+4096]+rR[km2], rI[k+4096]-rI[km2]);
        v2f S = Hk + Hk2, D = Hk - Hk2;
        v2f P = cmul(D, w);
        v[j] = S + imul(P);                            // 2*Z[k]
    }
    dft16<1>(v);
    twid_dif(v, T[p]);                                 // W4096^{p*m}
    #pragma unroll
    for (int m = 0; m < 16; ++m) buf[swz(p + (m<<8))] = v[REV(m)];
    __syncthreads();                                  // (2) A -> B

    // ---- DIF stage B (h=16) ----
    #pragma unroll
    for (int j = 0; j < 16; ++j) v[j] = buf[swz(i0 + (j<<4))];
    dft16<1>(v);
    twid_dif(v, wB);
    #pragma unroll
    for (int m = 0; m < 16; ++m) buf[swz(i0 + (m<<4))] = v[REV(m)];
    __syncthreads();                                  // (3) B -> C

    // ---- DIF stage C (h=1): thread-private slots {16p+j} ----
    #pragma unroll
    for (int j = 0; j < 16; ++j) v[j] = buf[swz((p<<4) + j)];
    dft16<1>(v);
    // time samples now in regs (sample at slot 16p+m is v[REV(m)])

    // ---- instance norm stats (order-agnostic) ----
    float ps = 0.f, pq = 0.f;
    #pragma unroll
    for (int j = 0; j < 16; ++j) {
        ps += v[j].x + v[j].y;
        pq += v[j].x*v[j].x + v[j].y*v[j].y;
    }
    #pragma unroll
    for (int off = 32; off >= 1; off >>= 1) {
        ps += __shfl_down(ps, off);
        pq += __shfl_down(pq, off);
    }
    // wave leader writes to its OWN private slot swz(16p) - no race
    if ((p & 63) == 0) buf[swz(p<<4)] = mk2(ps, pq);
    __syncthreads();                                  // (4) partials visible
    float sum = 0.f, sq = 0.f;
    #pragma unroll
    for (int w = 0; w < 4; ++w) {
        v2f pr = buf[swz((w<<6)<<4)];                  // leaders p=0,64,128,192
        sum += pr.x; sq += pr.y;
    }
    __syncthreads();                                  // (5) reads done before C' stores
    float mean = sum * (1.0f/8192.0f);
    float var  = sq  * (1.0f/8192.0f) - mean*mean;
    float gg = gamma[ch] * rsqrtf(var + 1e-5f);
    float bb = beta[ch] - mean * gg;
    #pragma unroll
    for (int j = 0; j < 16; ++j) v[j] = gelu2(v[j] * gg + bb);

    // ---- DIT stage C' (h=1): input position j = sample at slot 16p+j = v[REV(j)]
    {
        v2f u[16];
        #pragma unroll
        for (int j = 0; j < 16; ++j) u[j] = v[REV(j)];
        dft16<-1>(u);
        #pragma unroll
        for (int m = 0; m < 16; ++m) buf[swz((p<<4) + m)] = u[REV(m)];
    }
    __syncthreads();                                  // (6) C' -> B'

    // ---- DIT stage B' ----
    #pragma unroll
    for (int j = 0; j < 16; ++j) v[j] = buf[swz(i0 + (j<<4))];
    twid_dit(v, cconj(wB));
    dft16<-1>(v);
    #pragma unroll
    for (int m = 0; m < 16; ++m) buf[swz(i0 + (m<<4))] = v[REV(m)];
    __syncthreads();                                  // (7) B' -> A'

    // ---- DIT stage A': Z'[p+256m] at reg REV(m), straight to global ----
    #pragma unroll
    for (int j = 0; j < 16; ++j) v[j] = buf[swz(p + (j<<8))];
    twid_dit(v, cconj(T[p]));
    dft16<-1>(v);
    float* oR = outR + (size_t)row * kN;
    float* oI = outI + (size_t)row * kN;
    #pragma unroll
    for (int m = 0; m < 16; ++m) {
        int k = p + (m<<8);
        oR[k] = v[REV(m)].x;
        oI[k] = v[REV(m)].y;
    }
}

// Kernel 2: per (b, 16-pair colA tile): read Z' column-pairs (colA, 4096-colA),
// build 2*Y[colA] (cols 0..15) and 2*Y[4096-colA] (cols 16..31) via rfft
// post-combine, 128-pt FFT along c, scale + bit-rev + Hermitian-mirror writes.
// Tile 32KiB -> 4 blocks/CU. (Y-build math validated in r6.)
__global__ __launch_bounds__(256, 4) void k2_col(float* __restrict__ outR,
                                                 float* __restrict__ outI)
{
    __shared__ v2f tile[kC][32];  // 32 KiB
    __shared__ v2f tw[64];

    const int tid  = threadIdx.x;
    const int b    = blockIdx.y;
    const int k0   = blockIdx.x << 4;        // 0..2048 step 16 (129 blocks)
    const int jj   = tid & 15;
    const int cw   = tid >> 4;               // 0..15
    const int colA = k0 + jj;
    const bool valid = (colA <= 2048);
    const int colB = (4096 - colA) & 4095;

    if (tid < 64) {
        float s, c;
        sincosf((float)(kTwoPi/128.0 * (double)tid), &s, &c);
        tw[tid] = mk2(c, -s);
    }

    float ws, wc;  // w = e^{-i pi colA/4096}
    sincosf((float)(-kTwoPi/8192.0 * (double)colA), &ws, &wc);

    float* baseR = outR + (size_t)b * kC * kN;
    float* baseI = outI + (size_t)b * kC * kN;

    for (int c = cw; c < kC; c += 16) {
        v2f YA = mk2(0.f,0.f), YB = mk2(0.f,0.f);
        if (valid) {
            size_t offA = (size_t)c * kN + colA;
            size_t offB = (size_t)c * kN + colB;
            float Zx  = baseR[offA], Zy  = baseI[offA];
            float Zmx = baseR[offB], Zmy = baseI[offB];
            float Sx = Zx + Zmx, Sy = Zy - Zmy;
            float Dx = Zx - Zmx, Dy = Zy + Zmy;
            float Px = Dx*wc - Dy*ws, Py = Dx*ws + Dy*wc;
            YA = mk2(Sx + Py,  Sy - Px);     // 2*Y[colA]
            YB = mk2(Sx - Py, -Sy - Px);     // 2*Y[4096-colA]
        }
        tile[c][jj]      = YA;
        tile[c][jj + 16] = YB;
    }
    __syncthreads();

    // 128-pt forward DIF FFT along c, all 32 columns
    const int kc = tid & 31;
    const int wq = tid >> 5;                 // 0..7
    for (int st = 7; st >= 1; --st) {
        const int h = 1 << (st-1);
        #pragma unroll
        for (int s = 0; s < 8; ++s) {
            int q   = wq + (s<<3);
            int pos = q & (h-1);
            int g0  = ((q >> (st-1)) << st) + pos;
            int g1  = g0 + h;
            v2f a = tile[g0][kc], bb = tile[g1][kc];
            v2f w = tw[pos << (7-st)];
            tile[g0][kc] = a + bb;
            tile[g1][kc] = cmul(a - bb, w);
        }
        __syncthreads();
    }

    // write: col kc<16 -> kk=k0+kc (Y-A); kc>=16 -> kk=4096-(k0+kc-16) (Y-B)
    const int cA = (kc < 16) ? (k0 + kc) : (k0 + kc - 16);
    const int kk = (kc < 16) ? cA : (4096 - cA);
    if (cA <= 2048) {
        for (int pch = wq; pch < kC; pch += 8) {
            int f = (int)(__brev((unsigned)pch) >> 25);
            v2f vv = tile[pch][kc] * kScale;
            size_t off = (size_t)f * kN + kk;
            if (kk == 0 || kk == 4096) {
                baseR[off] = vv.x; baseI[off] = 0.f;
            } else {
                baseR[off] = vv.x; baseI[off] = vv.y;
                size_t offm = (size_t)f * kN + (kN - kk);
                baseR[offm] = vv.x; baseI[offm] = -vv.y;
            }
        }
    }
}

extern "C" void kernel_launch(void* const* d_in, const int* in_sizes, int n_in,
                              void* d_out, int out_size, void* d_ws, size_t ws_size,
                              hipStream_t stream)
{
    const float* xr    = (const float*)d_in[0];
    const float* xi    = (const float*)d_in[1];
    const float* gamma = (const float*)d_in[2];
    const float* beta  = (const float*)d_in[3];

    float* outR = (float*)d_out;
    float* outI = outR + (size_t)kB * kC * kN;

    k1_row<<<kB * kC, 256, 0, stream>>>(xr, xi, gamma, beta, outR, outI);
    k2_col<<<dim3(129, kB), 256, 0, stream>>>(outR, outI);
}